// Round 14
// baseline (147.995 us; speedup 1.0000x reference)
//
#include <hip/hip_runtime.h>
#include <hip/hip_bf16.h>

#define BN   8
#define NN   1024
#define CIN  256
#define COUT 256
#define HH   4
#define CC   64
#define ALPHA_C 0.2f

typedef __attribute__((ext_vector_type(8))) short short8;
typedef __attribute__((ext_vector_type(4))) float f32x4;

__device__ __forceinline__ unsigned short f2bf(float x) {
    __hip_bfloat16 h = __float2bfloat16(x);
    return *(unsigned short*)&h;
}
__device__ __forceinline__ float bf2f(unsigned short u) {
    return __uint_as_float(((unsigned int)u) << 16);
}

// ---------------- Kernel 0: pack W (fp32) -> Wh/Wl bf16 panels -----------------------
__global__ __launch_bounds__(256) void k0_wpack(
    const float* __restrict__ W, unsigned short* __restrict__ Whp, unsigned short* __restrict__ Wlp)
{
    const int bid = blockIdx.x;          // kc*4 + jg
    const int n = threadIdx.x;
    const int fi = n * 64 + (bid >> 2) * 8 + (bid & 3) * 2;
    const float4* W4 = (const float4*)W;
    float4 wa = W4[fi], wb = W4[fi + 1];
    float xs[8] = {wa.x, wa.y, wa.z, wa.w, wb.x, wb.y, wb.z, wb.w};
    unsigned short hh[8], ll[8];
    #pragma unroll
    for (int e = 0; e < 8; ++e) {
        hh[e] = f2bf(xs[e]);
        ll[e] = f2bf(xs[e] - bf2f(hh[e]));
    }
    *(uint4*)(Whp + ((size_t)bid * 256 + n) * 8) = *(uint4*)hh;
    *(uint4*)(Wlp + ((size_t)bid * 256 + n) * 8) = *(uint4*)ll;
}

// ---------------- Kernel 1: h = X@W^T + b via bf16x3 MFMA (unchanged) ----------------
__global__ __launch_bounds__(1024, 1) void k1_gemm(
    const float* __restrict__ X, const float* __restrict__ bias, const float* __restrict__ a,
    const unsigned short* __restrict__ Whp, const unsigned short* __restrict__ Wlp,
    unsigned short* __restrict__ hbf_p, float* __restrict__ lsrc_t, float* __restrict__ ldst_t)
{
    __shared__ __align__(16) unsigned short Xh[32 * 256];   // 16 KB, XOR-swizzled
    __shared__ __align__(16) unsigned short Xl[32 * 256];   // 16 KB
    __shared__ float lsP[2][8][2][16];                      // [src/dst][no][mq][m16]

    const int bid = blockIdx.x;
    const int row0 = bid * 32;
    const int b  = bid >> 5;
    const int tj = bid & 31;
    const int tid = threadIdx.x;
    const int wv = tid >> 6, l = tid & 63, il = l & 15, jg = l >> 4;
    const int mq = wv >> 3, no = wv & 7;

    {
        const float4* X4 = (const float4*)(X + (size_t)row0 * CIN);
        #pragma unroll
        for (int it = 0; it < 2; ++it) {
            int f = it * 1024 + tid;            // 0..2047 (32 rows x 64 float4)
            int r = f >> 6, k4 = f & 63;
            float4 x = X4[f];
            unsigned short h0 = f2bf(x.x), h1 = f2bf(x.y), h2 = f2bf(x.z), h3 = f2bf(x.w);
            unsigned short l0 = f2bf(x.x - bf2f(h0)), l1 = f2bf(x.y - bf2f(h1));
            unsigned short l2 = f2bf(x.z - bf2f(h2)), l3 = f2bf(x.w - bf2f(h3));
            unsigned short hs[4] = {h0, h1, h2, h3}, ls[4] = {l0, l1, l2, l3};
            int off = r * 512 + ((k4 * 8) ^ ((r & 7) << 4));
            *(uint2*)((char*)Xh + off) = *(uint2*)hs;
            *(uint2*)((char*)Xl + off) = *(uint2*)ls;
        }
    }
    __syncthreads();

    f32x4 acc0 = {0.f, 0.f, 0.f, 0.f}, acc1 = acc0;
    {
        const int abase = (mq * 16 + il) * 512;
        const int swz = (il & 7) << 4;
        const short8* Wh8 = (const short8*)Whp;
        const short8* Wl8 = (const short8*)Wlp;
        const int nb = no * 32 + il;
        #pragma unroll
        for (int kc = 0; kc < 8; ++kc) {
            const int ab = abase + ((kc * 64 + jg * 16) ^ swz);
            short8 Ah = *(const short8*)((const char*)Xh + ab);
            short8 Al = *(const short8*)((const char*)Xl + ab);
            const int pidx = (kc * 4 + jg) * 256 + nb;
            short8 Bh0 = Wh8[pidx],      Bl0 = Wl8[pidx];
            short8 Bh1 = Wh8[pidx + 16], Bl1 = Wl8[pidx + 16];
            acc0 = __builtin_amdgcn_mfma_f32_16x16x32_bf16(Ah, Bh0, acc0, 0, 0, 0);
            acc1 = __builtin_amdgcn_mfma_f32_16x16x32_bf16(Ah, Bh1, acc1, 0, 0, 0);
            acc0 = __builtin_amdgcn_mfma_f32_16x16x32_bf16(Ah, Bl0, acc0, 0, 0, 0);
            acc1 = __builtin_amdgcn_mfma_f32_16x16x32_bf16(Ah, Bl1, acc1, 0, 0, 0);
            acc0 = __builtin_amdgcn_mfma_f32_16x16x32_bf16(Al, Bh0, acc0, 0, 0, 0);
            acc1 = __builtin_amdgcn_mfma_f32_16x16x32_bf16(Al, Bh1, acc1, 0, 0, 0);
        }
    }

    const int c0 = no * 32 + il, c1 = c0 + 16;
    const float bia0 = bias[c0], bia1 = bias[c1];
    const int hh = no >> 1;
    const int cc0 = c0 & 63, cc1 = c1 & 63;
    const float as0 = a[hh * 128 + cc0],      as1 = a[hh * 128 + cc1];
    const float ad0 = a[hh * 128 + 64 + cc0], ad1 = a[hh * 128 + 64 + cc1];

    float v0[4], v1[4], psrc[4], pdst[4];
    #pragma unroll
    for (int r = 0; r < 4; ++r) {
        v0[r] = acc0[r] + bia0;
        v1[r] = acc1[r] + bia1;
        psrc[r] = v0[r] * as0 + v1[r] * as1;
        pdst[r] = v0[r] * ad0 + v1[r] * ad1;
    }
    #pragma unroll
    for (int off = 8; off >= 1; off >>= 1) {
        #pragma unroll
        for (int r = 0; r < 4; ++r) {
            psrc[r] += __shfl_xor(psrc[r], off);
            pdst[r] += __shfl_xor(pdst[r], off);
        }
    }
    __syncthreads();   // all waves done reading Xh/Xl

    unsigned short* hp = Xh;
    #pragma unroll
    for (int r = 0; r < 4; ++r) {
        int m = mq * 16 + 4 * jg + r;
        int base = (m >> 3) * 128 + (m & 7);
        hp[(c0 >> 6) * 2048 + ((c0 & 63) >> 4) * 512 + base + (c0 & 15) * 8] = f2bf(v0[r]);
        hp[(c1 >> 6) * 2048 + ((c1 & 63) >> 4) * 512 + base + (c1 & 15) * 8] = f2bf(v1[r]);
    }
    if (il == 0) {
        #pragma unroll
        for (int r = 0; r < 4; ++r) {
            lsP[0][no][mq][4 * jg + r] = psrc[r];
            lsP[1][no][mq][4 * jg + r] = pdst[r];
        }
    }
    __syncthreads();

    {
        uint4* dst4 = (uint4*)(hbf_p + (size_t)(b * 32 + tj) * 8192);
        dst4[tid] = ((const uint4*)hp)[tid];
    }
    if (tid < 256) {
        int sd = tid >> 7, rem = tid & 127, h2 = rem >> 5, m = rem & 31;
        float v = lsP[sd][2 * h2][m >> 4][m & 15] + lsP[sd][2 * h2 + 1][m >> 4][m & 15];
        float* dst = sd ? ldst_t : lsrc_t;
        dst[((size_t)b * HH + h2) * NN + tj * 32 + m] = v;
    }
}

// ---------------- Kernel 2: masked softmax attention, PV via MFMA -------------------
// grid 128 x 256thr (4 waves). b = bid&7 (all 16 blocks of a batch land on one XCD
// under round-robin mapping -> panels L2-resident), i0 = (bid>>3)*64.
// wave = head h; owns 64 rows x its 64 cols x ALL j. Per round: 4 coalesced B-frag
// loads amortized over 4 row-groups (32 PELEM + 16 MFMA ~ 500 cyc compute cover).
// Next round's VMEM+LDS loads issued then PINNED with sched_barrier(0) so hipcc
// cannot sink them (r13 failure: VGPR 36 = prefetch sunk). adj nt-loads + nt-stores
// keep the panel set resident in L2. One barrier total; heads output-disjoint.
__global__ __launch_bounds__(256, 1) void k2_attn(
    const unsigned short* __restrict__ hbf_p, const int* __restrict__ adj,
    const float* __restrict__ lsrc_t, const float* __restrict__ ldst_t,
    float* __restrict__ out)
{
    __shared__ unsigned int adjw[32][64];     // [j-word][i-row] bits, 8 KB
    __shared__ float ldsTbl[4 * 1024];        // ldst per head, 16 KB

    const int bid = blockIdx.x;
    const int b  = bid & 7;
    const int i0 = (bid >> 3) * 64;
    const int tid = threadIdx.x;
    const int h  = tid >> 6;                  // wave = head
    const int l  = tid & 63, il = l & 15, jg = l >> 4;

    // ---- prologue: adj bit-pack (wave h packs rows 16h..16h+15, nt loads) ----
    {
        const int* arow = adj + ((size_t)b * NN + i0 + 16 * h) * NN;
        #pragma unroll 4
        for (int rr = 0; rr < 16; ++rr) {
            #pragma unroll
            for (int it = 0; it < 16; ++it) {
                int av = __builtin_nontemporal_load(&arow[(size_t)rr * NN + it * 64 + l]);
                unsigned long long mb = __ballot(av != 0);
                if (l == 0) {
                    adjw[2 * it    ][16 * h + rr] = (unsigned int)mb;
                    adjw[2 * it + 1][16 * h + rr] = (unsigned int)(mb >> 32);
                }
            }
        }
    }
    {
        const float4* src = (const float4*)(ldst_t + (size_t)b * HH * NN);
        #pragma unroll
        for (int k = 0; k < 4; ++k)
            ((float4*)ldsTbl)[k * 256 + tid] = src[k * 256 + tid];
    }
    const float* lsrc_b = lsrc_t + ((size_t)b * HH + h) * NN + i0;
    float lsv0 = lsrc_b[il], lsv1 = lsrc_b[16 + il], lsv2 = lsrc_b[32 + il], lsv3 = lsrc_b[48 + il];

    __syncthreads();   // adjw + ldsTbl ready (only barrier in the kernel)

    // ---- mx = max over all j of ldst[h] (valid softmax shift: lrelu monotone) ----
    float mx = -3.4e38f;
    #pragma unroll
    for (int jt = 0; jt < 16; ++jt) mx = fmaxf(mx, ldsTbl[h * 1024 + jt * 64 + l]);
    #pragma unroll
    for (int off = 32; off >= 1; off >>= 1) mx = fmaxf(mx, __shfl_xor(mx, off));
    #define MKMR(G) float mr##G; { float t_ = lsv##G + mx; mr##G = fmaxf(t_, ALPHA_C * t_); }
    MKMR(0) MKMR(1) MKMR(2) MKMR(3)
    #undef MKMR
    float ls0 = 0.f, ls1 = 0.f, ls2 = 0.f, ls3 = 0.f;

    f32x4 zero4 = {0.f,0.f,0.f,0.f};
    f32x4 acc00 = zero4, acc01 = zero4, acc02 = zero4, acc03 = zero4;
    f32x4 acc10 = zero4, acc11 = zero4, acc12 = zero4, acc13 = zero4;
    f32x4 acc20 = zero4, acc21 = zero4, acc22 = zero4, acc23 = zero4;
    f32x4 acc30 = zero4, acc31 = zero4, acc32 = zero4, acc33 = zero4;

    // B-frag: panel t, head h, sub s, lane l at short8 index t*1024 + h*256 + s*64 + l
    const short8* bfp = (const short8*)(hbf_p + (size_t)b * 32 * 8192);
    const int fb = h * 256 + l;
    const float* ltb = ldsTbl + h * 1024 + jg * 8;

    // preload round 0 state
    short8 c0 = bfp[fb +   0];
    short8 c1 = bfp[fb +  64];
    short8 c2 = bfp[fb + 128];
    short8 c3 = bfp[fb + 192];
    unsigned int bw0 = adjw[0][ 0 + il], bw1 = adjw[0][16 + il];
    unsigned int bw2 = adjw[0][32 + il], bw3 = adjw[0][48 + il];
    float4 dA = *(const float4*)(ltb);
    float4 dB = *(const float4*)(ltb + 4);

    #define PEL(AF, E, DV, BWV, LSV, MR, LS) {                   \
        float s_ = (LSV) + (DV);                                 \
        s_ = fmaxf(s_, ALPHA_C * s_);                            \
        float p_ = __expf(s_ - (MR));                            \
        p_ = ((BWV >> (E)) & 1u) ? p_ : 0.f;                     \
        LS += p_;                                                \
        AF[E] = (short)f2bf(p_); }

    #define ROWG(G) {                                            \
        const unsigned int bwv = bw##G >> (jg * 8);              \
        short8 af;                                               \
        PEL(af, 0, dA.x, bwv, lsv##G, mr##G, ls##G)              \
        PEL(af, 1, dA.y, bwv, lsv##G, mr##G, ls##G)              \
        PEL(af, 2, dA.z, bwv, lsv##G, mr##G, ls##G)              \
        PEL(af, 3, dA.w, bwv, lsv##G, mr##G, ls##G)              \
        PEL(af, 4, dB.x, bwv, lsv##G, mr##G, ls##G)              \
        PEL(af, 5, dB.y, bwv, lsv##G, mr##G, ls##G)              \
        PEL(af, 6, dB.z, bwv, lsv##G, mr##G, ls##G)              \
        PEL(af, 7, dB.w, bwv, lsv##G, mr##G, ls##G)              \
        acc##G##0 = __builtin_amdgcn_mfma_f32_16x16x32_bf16(af, c0, acc##G##0, 0, 0, 0); \
        acc##G##1 = __builtin_amdgcn_mfma_f32_16x16x32_bf16(af, c1, acc##G##1, 0, 0, 0); \
        acc##G##2 = __builtin_amdgcn_mfma_f32_16x16x32_bf16(af, c2, acc##G##2, 0, 0, 0); \
        acc##G##3 = __builtin_amdgcn_mfma_f32_16x16x32_bf16(af, c3, acc##G##3, 0, 0, 0); }

    for (int t = 0; t < 32; ++t) {
        // ---- issue round t+1 loads (VMEM B-frags + LDS adj/ldst), then pin ----
        const int tn = (t < 31) ? t + 1 : 31;
        short8 n0 = bfp[tn * 1024 + fb +   0];
        short8 n1 = bfp[tn * 1024 + fb +  64];
        short8 n2 = bfp[tn * 1024 + fb + 128];
        short8 n3 = bfp[tn * 1024 + fb + 192];
        unsigned int bn0 = adjw[tn][ 0 + il], bn1 = adjw[tn][16 + il];
        unsigned int bn2 = adjw[tn][32 + il], bn3 = adjw[tn][48 + il];
        float4 dAn = *(const float4*)(ltb + tn * 32);
        float4 dBn = *(const float4*)(ltb + tn * 32 + 4);
        __builtin_amdgcn_sched_barrier(0);   // loads above may NOT sink below

        // ---- compute round t from registers loaded last iteration ----
        ROWG(0) ROWG(1) ROWG(2) ROWG(3)

        c0 = n0; c1 = n1; c2 = n2; c3 = n3;
        bw0 = bn0; bw1 = bn1; bw2 = bn2; bw3 = bn3;
        dA = dAn; dB = dBn;
    }
    #undef PEL
    #undef ROWG

    // ---- per-rowgroup: reduce lsum over jg, normalize, nt-store ----
    #define OUTG(G) {                                                        \
        float lsv = ls##G;                                                   \
        lsv += __shfl_xor(lsv, 16);                                          \
        lsv += __shfl_xor(lsv, 32);                                          \
        float inv0 = 1.0f / __shfl(lsv, 4 * jg + 0);                         \
        float inv1 = 1.0f / __shfl(lsv, 4 * jg + 1);                         \
        float inv2 = 1.0f / __shfl(lsv, 4 * jg + 2);                         \
        float inv3 = 1.0f / __shfl(lsv, 4 * jg + 3);                         \
        float* outp = out + ((size_t)(b * NN + i0 + G * 16)) * COUT + h * 64 + il; \
        const size_t r0 = (size_t)(4 * jg + 0) * COUT;                       \
        const size_t r1 = (size_t)(4 * jg + 1) * COUT;                       \
        const size_t r2 = (size_t)(4 * jg + 2) * COUT;                       \
        const size_t r3 = (size_t)(4 * jg + 3) * COUT;                       \
        __builtin_nontemporal_store(acc##G##0[0] * inv0, outp + r0 +  0);    \
        __builtin_nontemporal_store(acc##G##1[0] * inv0, outp + r0 + 16);    \
        __builtin_nontemporal_store(acc##G##2[0] * inv0, outp + r0 + 32);    \
        __builtin_nontemporal_store(acc##G##3[0] * inv0, outp + r0 + 48);    \
        __builtin_nontemporal_store(acc##G##0[1] * inv1, outp + r1 +  0);    \
        __builtin_nontemporal_store(acc##G##1[1] * inv1, outp + r1 + 16);    \
        __builtin_nontemporal_store(acc##G##2[1] * inv1, outp + r1 + 32);    \
        __builtin_nontemporal_store(acc##G##3[1] * inv1, outp + r1 + 48);    \
        __builtin_nontemporal_store(acc##G##0[2] * inv2, outp + r2 +  0);    \
        __builtin_nontemporal_store(acc##G##1[2] * inv2, outp + r2 + 16);    \
        __builtin_nontemporal_store(acc##G##2[2] * inv2, outp + r2 + 32);    \
        __builtin_nontemporal_store(acc##G##3[2] * inv2, outp + r2 + 48);    \
        __builtin_nontemporal_store(acc##G##0[3] * inv3, outp + r3 +  0);    \
        __builtin_nontemporal_store(acc##G##1[3] * inv3, outp + r3 + 16);    \
        __builtin_nontemporal_store(acc##G##2[3] * inv3, outp + r3 + 32);    \
        __builtin_nontemporal_store(acc##G##3[3] * inv3, outp + r3 + 48); }
    OUTG(0) OUTG(1) OUTG(2) OUTG(3)
    #undef OUTG
}

extern "C" void kernel_launch(void* const* d_in, const int* in_sizes, int n_in,
                              void* d_out, int out_size, void* d_ws, size_t ws_size,
                              hipStream_t stream) {
    const float* X    = (const float*)d_in[0];
    const int*   adj  = (const int*)  d_in[1];
    const float* W    = (const float*)d_in[2];
    const float* bias = (const float*)d_in[3];
    const float* a    = (const float*)d_in[4];
    float* out = (float*)d_out;

    unsigned short* hbf_p = (unsigned short*)d_ws;                  // 8*32 panels, 4 MB
    float* lsrc_t = (float*)(hbf_p + (size_t)BN * 32 * 8192);       // [b][h][n]
    float* ldst_t = lsrc_t + (size_t)BN * HH * NN;
    unsigned short* Whp = (unsigned short*)(ldst_t + (size_t)BN * HH * NN);  // 128 KB
    unsigned short* Wlp = Whp + 65536;                                        // 128 KB

    k0_wpack<<<32, 256, 0, stream>>>(W, Whp, Wlp);
    k1_gemm<<<256, 1024, 0, stream>>>(X, bias, a, Whp, Wlp, hbf_p, lsrc_t, ldst_t);
    k2_attn<<<BN * (NN / 64), 256, 0, stream>>>(hbf_p, adj, lsrc_t, ldst_t, out);
}

// Round 15
// 71.795 us; speedup vs baseline: 2.0614x; 2.0614x over previous
//
#include <hip/hip_runtime.h>
#include <hip/hip_bf16.h>

#define BN   8
#define NN   1024
#define CIN  256
#define COUT 256
#define HH   4
#define CC   64
#define ALPHA_C 0.2f

typedef __attribute__((ext_vector_type(8))) short short8;
typedef __attribute__((ext_vector_type(4))) float f32x4;

__device__ __forceinline__ unsigned short f2bf(float x) {
    __hip_bfloat16 h = __float2bfloat16(x);
    return *(unsigned short*)&h;
}
__device__ __forceinline__ float bf2f(unsigned short u) {
    return __uint_as_float(((unsigned int)u) << 16);
}

// ---------------- Kernel 0: pack W (fp32) -> Wh/Wl bf16 panels -----------------------
__global__ __launch_bounds__(256) void k0_wpack(
    const float* __restrict__ W, unsigned short* __restrict__ Whp, unsigned short* __restrict__ Wlp)
{
    const int bid = blockIdx.x;          // kc*4 + jg
    const int n = threadIdx.x;
    const int fi = n * 64 + (bid >> 2) * 8 + (bid & 3) * 2;
    const float4* W4 = (const float4*)W;
    float4 wa = W4[fi], wb = W4[fi + 1];
    float xs[8] = {wa.x, wa.y, wa.z, wa.w, wb.x, wb.y, wb.z, wb.w};
    unsigned short hh[8], ll[8];
    #pragma unroll
    for (int e = 0; e < 8; ++e) {
        hh[e] = f2bf(xs[e]);
        ll[e] = f2bf(xs[e] - bf2f(hh[e]));
    }
    *(uint4*)(Whp + ((size_t)bid * 256 + n) * 8) = *(uint4*)hh;
    *(uint4*)(Wlp + ((size_t)bid * 256 + n) * 8) = *(uint4*)ll;
}

// ---------------- Kernel 1: h = X@W^T + b via bf16x3 MFMA (unchanged) ----------------
__global__ __launch_bounds__(1024, 1) void k1_gemm(
    const float* __restrict__ X, const float* __restrict__ bias, const float* __restrict__ a,
    const unsigned short* __restrict__ Whp, const unsigned short* __restrict__ Wlp,
    unsigned short* __restrict__ hbf_p, float* __restrict__ lsrc_t, float* __restrict__ ldst_t)
{
    __shared__ __align__(16) unsigned short Xh[32 * 256];   // 16 KB, XOR-swizzled
    __shared__ __align__(16) unsigned short Xl[32 * 256];   // 16 KB
    __shared__ float lsP[2][8][2][16];                      // [src/dst][no][mq][m16]

    const int bid = blockIdx.x;
    const int row0 = bid * 32;
    const int b  = bid >> 5;
    const int tj = bid & 31;
    const int tid = threadIdx.x;
    const int wv = tid >> 6, l = tid & 63, il = l & 15, jg = l >> 4;
    const int mq = wv >> 3, no = wv & 7;

    {
        const float4* X4 = (const float4*)(X + (size_t)row0 * CIN);
        #pragma unroll
        for (int it = 0; it < 2; ++it) {
            int f = it * 1024 + tid;            // 0..2047 (32 rows x 64 float4)
            int r = f >> 6, k4 = f & 63;
            float4 x = X4[f];
            unsigned short h0 = f2bf(x.x), h1 = f2bf(x.y), h2 = f2bf(x.z), h3 = f2bf(x.w);
            unsigned short l0 = f2bf(x.x - bf2f(h0)), l1 = f2bf(x.y - bf2f(h1));
            unsigned short l2 = f2bf(x.z - bf2f(h2)), l3 = f2bf(x.w - bf2f(h3));
            unsigned short hs[4] = {h0, h1, h2, h3}, ls[4] = {l0, l1, l2, l3};
            int off = r * 512 + ((k4 * 8) ^ ((r & 7) << 4));
            *(uint2*)((char*)Xh + off) = *(uint2*)hs;
            *(uint2*)((char*)Xl + off) = *(uint2*)ls;
        }
    }
    __syncthreads();

    f32x4 acc0 = {0.f, 0.f, 0.f, 0.f}, acc1 = acc0;
    {
        const int abase = (mq * 16 + il) * 512;
        const int swz = (il & 7) << 4;
        const short8* Wh8 = (const short8*)Whp;
        const short8* Wl8 = (const short8*)Wlp;
        const int nb = no * 32 + il;
        #pragma unroll
        for (int kc = 0; kc < 8; ++kc) {
            const int ab = abase + ((kc * 64 + jg * 16) ^ swz);
            short8 Ah = *(const short8*)((const char*)Xh + ab);
            short8 Al = *(const short8*)((const char*)Xl + ab);
            const int pidx = (kc * 4 + jg) * 256 + nb;
            short8 Bh0 = Wh8[pidx],      Bl0 = Wl8[pidx];
            short8 Bh1 = Wh8[pidx + 16], Bl1 = Wl8[pidx + 16];
            acc0 = __builtin_amdgcn_mfma_f32_16x16x32_bf16(Ah, Bh0, acc0, 0, 0, 0);
            acc1 = __builtin_amdgcn_mfma_f32_16x16x32_bf16(Ah, Bh1, acc1, 0, 0, 0);
            acc0 = __builtin_amdgcn_mfma_f32_16x16x32_bf16(Ah, Bl0, acc0, 0, 0, 0);
            acc1 = __builtin_amdgcn_mfma_f32_16x16x32_bf16(Ah, Bl1, acc1, 0, 0, 0);
            acc0 = __builtin_amdgcn_mfma_f32_16x16x32_bf16(Al, Bh0, acc0, 0, 0, 0);
            acc1 = __builtin_amdgcn_mfma_f32_16x16x32_bf16(Al, Bh1, acc1, 0, 0, 0);
        }
    }

    const int c0 = no * 32 + il, c1 = c0 + 16;
    const float bia0 = bias[c0], bia1 = bias[c1];
    const int hh = no >> 1;
    const int cc0 = c0 & 63, cc1 = c1 & 63;
    const float as0 = a[hh * 128 + cc0],      as1 = a[hh * 128 + cc1];
    const float ad0 = a[hh * 128 + 64 + cc0], ad1 = a[hh * 128 + 64 + cc1];

    float v0[4], v1[4], psrc[4], pdst[4];
    #pragma unroll
    for (int r = 0; r < 4; ++r) {
        v0[r] = acc0[r] + bia0;
        v1[r] = acc1[r] + bia1;
        psrc[r] = v0[r] * as0 + v1[r] * as1;
        pdst[r] = v0[r] * ad0 + v1[r] * ad1;
    }
    #pragma unroll
    for (int off = 8; off >= 1; off >>= 1) {
        #pragma unroll
        for (int r = 0; r < 4; ++r) {
            psrc[r] += __shfl_xor(psrc[r], off);
            pdst[r] += __shfl_xor(pdst[r], off);
        }
    }
    __syncthreads();   // all waves done reading Xh/Xl

    unsigned short* hp = Xh;
    #pragma unroll
    for (int r = 0; r < 4; ++r) {
        int m = mq * 16 + 4 * jg + r;
        int base = (m >> 3) * 128 + (m & 7);
        hp[(c0 >> 6) * 2048 + ((c0 & 63) >> 4) * 512 + base + (c0 & 15) * 8] = f2bf(v0[r]);
        hp[(c1 >> 6) * 2048 + ((c1 & 63) >> 4) * 512 + base + (c1 & 15) * 8] = f2bf(v1[r]);
    }
    if (il == 0) {
        #pragma unroll
        for (int r = 0; r < 4; ++r) {
            lsP[0][no][mq][4 * jg + r] = psrc[r];
            lsP[1][no][mq][4 * jg + r] = pdst[r];
        }
    }
    __syncthreads();

    {
        uint4* dst4 = (uint4*)(hbf_p + (size_t)(b * 32 + tj) * 8192);
        dst4[tid] = ((const uint4*)hp)[tid];
    }
    if (tid < 256) {
        int sd = tid >> 7, rem = tid & 127, h2 = rem >> 5, m = rem & 31;
        float v = lsP[sd][2 * h2][m >> 4][m & 15] + lsP[sd][2 * h2 + 1][m >> 4][m & 15];
        float* dst = sd ? ldst_t : lsrc_t;
        dst[((size_t)b * HH + h2) * NN + tj * 32 + m] = v;
    }
}

// ---------------- Kernel 2: masked softmax attention, PV via MFMA -------------------
// grid 256 x 256thr (4 waves). b = bid&7, i0 = (bid>>3)*32. wave = head h; owns
// 32 rows (2 rowgroups) x its 64 cols x ALL 32 panels -> heads output-disjoint:
// no cross-wave reduction, ONE barrier. __launch_bounds__(256,2): 2 blocks/CU
// co-resident (8 waves/CU) AND a register budget that fits the ~110-VGPR live set.
// 1-deep register prefetch pinned with sched_barrier(0) (r14-proven; r10/r13's
// unpinned prefetch was sunk -> VGPR 36-40 -> full latency exposure).
// Per round: 4 coalesced 1KB B-frag loads amortized over 2 rowgroups
// (16 PELEM + 8 MFMA ~ 300 cyc cover). Panel L2 traffic 128 MB (half of r13).
__global__ __launch_bounds__(256, 2) void k2_attn(
    const unsigned short* __restrict__ hbf_p, const int* __restrict__ adj,
    const float* __restrict__ lsrc_t, const float* __restrict__ ldst_t,
    float* __restrict__ out)
{
    __shared__ unsigned int adjw[32][32];     // [j-word][i-row] bits, 4 KB
    __shared__ float ldsTbl[4 * 1024];        // ldst per head, 16 KB

    const int bid = blockIdx.x;
    const int b  = bid & 7;
    const int i0 = (bid >> 3) * 32;
    const int tid = threadIdx.x;
    const int h  = tid >> 6;                  // wave = head
    const int l  = tid & 63, il = l & 15, jg = l >> 4;

    // ---- prologue: adj bit-pack (wave h packs rows 8h..8h+7) + ldst table ----
    {
        const int* arow = adj + ((size_t)b * NN + i0 + 8 * h) * NN;
        #pragma unroll 2
        for (int rr = 0; rr < 8; ++rr) {
            #pragma unroll
            for (int it = 0; it < 16; ++it) {
                int av = arow[(size_t)rr * NN + it * 64 + l];
                unsigned long long mb = __ballot(av != 0);
                if (l == 0) {
                    adjw[2 * it    ][8 * h + rr] = (unsigned int)mb;
                    adjw[2 * it + 1][8 * h + rr] = (unsigned int)(mb >> 32);
                }
            }
        }
    }
    {
        const float4* src = (const float4*)(ldst_t + (size_t)b * HH * NN);
        #pragma unroll
        for (int k = 0; k < 4; ++k)
            ((float4*)ldsTbl)[k * 256 + tid] = src[k * 256 + tid];
    }
    const float* lsrc_b = lsrc_t + ((size_t)b * HH + h) * NN + i0;
    const float lsv0 = lsrc_b[il];
    const float lsv1 = lsrc_b[16 + il];

    __syncthreads();   // adjw + ldsTbl ready (only barrier in the kernel)

    // ---- mx = max over all j of ldst[h] (valid softmax shift: lrelu monotone) ----
    float mx = -3.4e38f;
    #pragma unroll
    for (int jt = 0; jt < 16; ++jt) mx = fmaxf(mx, ldsTbl[h * 1024 + jt * 64 + l]);
    #pragma unroll
    for (int off = 32; off >= 1; off >>= 1) mx = fmaxf(mx, __shfl_xor(mx, off));
    float mr0, mr1;
    { float t_ = lsv0 + mx; mr0 = fmaxf(t_, ALPHA_C * t_); }
    { float t_ = lsv1 + mx; mr1 = fmaxf(t_, ALPHA_C * t_); }
    float ls0 = 0.f, ls1 = 0.f;

    f32x4 zero4 = {0.f,0.f,0.f,0.f};
    f32x4 acc00 = zero4, acc01 = zero4, acc02 = zero4, acc03 = zero4;
    f32x4 acc10 = zero4, acc11 = zero4, acc12 = zero4, acc13 = zero4;

    // B-frag: panel t, head h, sub s, lane l at short8 index t*1024 + h*256 + s*64 + l
    const short8* bfp = (const short8*)(hbf_p + (size_t)b * 32 * 8192);
    const int fb = h * 256 + l;
    const float* ltb = ldsTbl + h * 1024 + jg * 8;

    // preload round 0
    short8 c0 = bfp[fb +   0];
    short8 c1 = bfp[fb +  64];
    short8 c2 = bfp[fb + 128];
    short8 c3 = bfp[fb + 192];
    unsigned int bw0 = adjw[0][il], bw1 = adjw[0][16 + il];
    float4 dA = *(const float4*)(ltb);
    float4 dB = *(const float4*)(ltb + 4);

    #define PEL(AF, E, DV, BWV, LSV, MR, LS) {                   \
        float s_ = (LSV) + (DV);                                 \
        s_ = fmaxf(s_, ALPHA_C * s_);                            \
        float p_ = __expf(s_ - (MR));                            \
        p_ = ((BWV >> (E)) & 1u) ? p_ : 0.f;                     \
        LS += p_;                                                \
        AF[E] = (short)f2bf(p_); }

    #define ROWG(G) {                                            \
        const unsigned int bwv = bw##G >> (jg * 8);              \
        short8 af;                                               \
        PEL(af, 0, dA.x, bwv, lsv##G, mr##G, ls##G)              \
        PEL(af, 1, dA.y, bwv, lsv##G, mr##G, ls##G)              \
        PEL(af, 2, dA.z, bwv, lsv##G, mr##G, ls##G)              \
        PEL(af, 3, dA.w, bwv, lsv##G, mr##G, ls##G)              \
        PEL(af, 4, dB.x, bwv, lsv##G, mr##G, ls##G)              \
        PEL(af, 5, dB.y, bwv, lsv##G, mr##G, ls##G)              \
        PEL(af, 6, dB.z, bwv, lsv##G, mr##G, ls##G)              \
        PEL(af, 7, dB.w, bwv, lsv##G, mr##G, ls##G)              \
        acc##G##0 = __builtin_amdgcn_mfma_f32_16x16x32_bf16(af, c0, acc##G##0, 0, 0, 0); \
        acc##G##1 = __builtin_amdgcn_mfma_f32_16x16x32_bf16(af, c1, acc##G##1, 0, 0, 0); \
        acc##G##2 = __builtin_amdgcn_mfma_f32_16x16x32_bf16(af, c2, acc##G##2, 0, 0, 0); \
        acc##G##3 = __builtin_amdgcn_mfma_f32_16x16x32_bf16(af, c3, acc##G##3, 0, 0, 0); }

    for (int t = 0; t < 32; ++t) {
        // ---- issue round t+1 loads, then pin so hipcc can't sink them ----
        const int tn = (t < 31) ? t + 1 : 31;
        short8 n0 = bfp[tn * 1024 + fb +   0];
        short8 n1 = bfp[tn * 1024 + fb +  64];
        short8 n2 = bfp[tn * 1024 + fb + 128];
        short8 n3 = bfp[tn * 1024 + fb + 192];
        unsigned int bn0 = adjw[tn][il], bn1 = adjw[tn][16 + il];
        float4 dAn = *(const float4*)(ltb + tn * 32);
        float4 dBn = *(const float4*)(ltb + tn * 32 + 4);
        __builtin_amdgcn_sched_barrier(0);

        // ---- compute round t from registers loaded last iteration ----
        ROWG(0) ROWG(1)

        c0 = n0; c1 = n1; c2 = n2; c3 = n3;
        bw0 = bn0; bw1 = bn1;
        dA = dAn; dB = dBn;
    }
    #undef PEL
    #undef ROWG

    // ---- per-rowgroup: reduce lsum over jg, normalize, store ----
    #define OUTG(G) {                                                        \
        float lsv = ls##G;                                                   \
        lsv += __shfl_xor(lsv, 16);                                          \
        lsv += __shfl_xor(lsv, 32);                                          \
        float inv0 = 1.0f / __shfl(lsv, 4 * jg + 0);                         \
        float inv1 = 1.0f / __shfl(lsv, 4 * jg + 1);                         \
        float inv2 = 1.0f / __shfl(lsv, 4 * jg + 2);                         \
        float inv3 = 1.0f / __shfl(lsv, 4 * jg + 3);                         \
        float* outp = out + ((size_t)(b * NN + i0 + G * 16)) * COUT + h * 64 + il; \
        const size_t r0 = (size_t)(4 * jg + 0) * COUT;                       \
        const size_t r1 = (size_t)(4 * jg + 1) * COUT;                       \
        const size_t r2 = (size_t)(4 * jg + 2) * COUT;                       \
        const size_t r3 = (size_t)(4 * jg + 3) * COUT;                       \
        outp[r0 +  0] = acc##G##0[0] * inv0; outp[r0 + 16] = acc##G##1[0] * inv0; \
        outp[r0 + 32] = acc##G##2[0] * inv0; outp[r0 + 48] = acc##G##3[0] * inv0; \
        outp[r1 +  0] = acc##G##0[1] * inv1; outp[r1 + 16] = acc##G##1[1] * inv1; \
        outp[r1 + 32] = acc##G##2[1] * inv1; outp[r1 + 48] = acc##G##3[1] * inv1; \
        outp[r2 +  0] = acc##G##0[2] * inv2; outp[r2 + 16] = acc##G##1[2] * inv2; \
        outp[r2 + 32] = acc##G##2[2] * inv2; outp[r2 + 48] = acc##G##3[2] * inv2; \
        outp[r3 +  0] = acc##G##0[3] * inv3; outp[r3 + 16] = acc##G##1[3] * inv3; \
        outp[r3 + 32] = acc##G##2[3] * inv3; outp[r3 + 48] = acc##G##3[3] * inv3; }
    OUTG(0) OUTG(1)
    #undef OUTG
}

extern "C" void kernel_launch(void* const* d_in, const int* in_sizes, int n_in,
                              void* d_out, int out_size, void* d_ws, size_t ws_size,
                              hipStream_t stream) {
    const float* X    = (const float*)d_in[0];
    const int*   adj  = (const int*)  d_in[1];
    const float* W    = (const float*)d_in[2];
    const float* bias = (const float*)d_in[3];
    const float* a    = (const float*)d_in[4];
    float* out = (float*)d_out;

    unsigned short* hbf_p = (unsigned short*)d_ws;                  // 8*32 panels, 4 MB
    float* lsrc_t = (float*)(hbf_p + (size_t)BN * 32 * 8192);       // [b][h][n]
    float* ldst_t = lsrc_t + (size_t)BN * HH * NN;
    unsigned short* Whp = (unsigned short*)(ldst_t + (size_t)BN * HH * NN);  // 128 KB
    unsigned short* Wlp = Whp + 65536;                                        // 128 KB

    k0_wpack<<<32, 256, 0, stream>>>(W, Whp, Wlp);
    k1_gemm<<<256, 1024, 0, stream>>>(X, bias, a, Whp, Wlp, hbf_p, lsrc_t, ldst_t);
    k2_attn<<<BN * (NN / 32), 256, 0, stream>>>(hbf_p, adj, lsrc_t, ldst_t, out);
}

// Round 16
// 49.721 us; speedup vs baseline: 2.9765x; 1.4440x over previous
//
#include <hip/hip_runtime.h>
#include <hip/hip_bf16.h>

#define BN   8
#define NN   1024
#define CIN  256
#define COUT 256
#define HH   4
#define CC   64
#define ALPHA_C 0.2f

typedef __attribute__((ext_vector_type(8))) short short8;
typedef __attribute__((ext_vector_type(4))) float f32x4;

__device__ __forceinline__ unsigned short f2bf(float x) {
    __hip_bfloat16 h = __float2bfloat16(x);
    return *(unsigned short*)&h;
}
__device__ __forceinline__ float bf2f(unsigned short u) {
    return __uint_as_float(((unsigned int)u) << 16);
}

// ---------------- Kernel 0: pack W (fp32) -> Wh/Wl bf16 panels -----------------------
__global__ __launch_bounds__(256) void k0_wpack(
    const float* __restrict__ W, unsigned short* __restrict__ Whp, unsigned short* __restrict__ Wlp)
{
    const int bid = blockIdx.x;          // kc*4 + jg
    const int n = threadIdx.x;
    const int fi = n * 64 + (bid >> 2) * 8 + (bid & 3) * 2;
    const float4* W4 = (const float4*)W;
    float4 wa = W4[fi], wb = W4[fi + 1];
    float xs[8] = {wa.x, wa.y, wa.z, wa.w, wb.x, wb.y, wb.z, wb.w};
    unsigned short hh[8], ll[8];
    #pragma unroll
    for (int e = 0; e < 8; ++e) {
        hh[e] = f2bf(xs[e]);
        ll[e] = f2bf(xs[e] - bf2f(hh[e]));
    }
    *(uint4*)(Whp + ((size_t)bid * 256 + n) * 8) = *(uint4*)hh;
    *(uint4*)(Wlp + ((size_t)bid * 256 + n) * 8) = *(uint4*)ll;
}

// ---------------- Kernel 1: h = X@W^T + b via bf16x3 MFMA (unchanged) ----------------
__global__ __launch_bounds__(1024, 1) void k1_gemm(
    const float* __restrict__ X, const float* __restrict__ bias, const float* __restrict__ a,
    const unsigned short* __restrict__ Whp, const unsigned short* __restrict__ Wlp,
    unsigned short* __restrict__ hbf_p, float* __restrict__ lsrc_t, float* __restrict__ ldst_t)
{
    __shared__ __align__(16) unsigned short Xh[32 * 256];   // 16 KB, XOR-swizzled
    __shared__ __align__(16) unsigned short Xl[32 * 256];   // 16 KB
    __shared__ float lsP[2][8][2][16];                      // [src/dst][no][mq][m16]

    const int bid = blockIdx.x;
    const int row0 = bid * 32;
    const int b  = bid >> 5;
    const int tj = bid & 31;
    const int tid = threadIdx.x;
    const int wv = tid >> 6, l = tid & 63, il = l & 15, jg = l >> 4;
    const int mq = wv >> 3, no = wv & 7;

    {
        const float4* X4 = (const float4*)(X + (size_t)row0 * CIN);
        #pragma unroll
        for (int it = 0; it < 2; ++it) {
            int f = it * 1024 + tid;            // 0..2047 (32 rows x 64 float4)
            int r = f >> 6, k4 = f & 63;
            float4 x = X4[f];
            unsigned short h0 = f2bf(x.x), h1 = f2bf(x.y), h2 = f2bf(x.z), h3 = f2bf(x.w);
            unsigned short l0 = f2bf(x.x - bf2f(h0)), l1 = f2bf(x.y - bf2f(h1));
            unsigned short l2 = f2bf(x.z - bf2f(h2)), l3 = f2bf(x.w - bf2f(h3));
            unsigned short hs[4] = {h0, h1, h2, h3}, ls[4] = {l0, l1, l2, l3};
            int off = r * 512 + ((k4 * 8) ^ ((r & 7) << 4));
            *(uint2*)((char*)Xh + off) = *(uint2*)hs;
            *(uint2*)((char*)Xl + off) = *(uint2*)ls;
        }
    }
    __syncthreads();

    f32x4 acc0 = {0.f, 0.f, 0.f, 0.f}, acc1 = acc0;
    {
        const int abase = (mq * 16 + il) * 512;
        const int swz = (il & 7) << 4;
        const short8* Wh8 = (const short8*)Whp;
        const short8* Wl8 = (const short8*)Wlp;
        const int nb = no * 32 + il;
        #pragma unroll
        for (int kc = 0; kc < 8; ++kc) {
            const int ab = abase + ((kc * 64 + jg * 16) ^ swz);
            short8 Ah = *(const short8*)((const char*)Xh + ab);
            short8 Al = *(const short8*)((const char*)Xl + ab);
            const int pidx = (kc * 4 + jg) * 256 + nb;
            short8 Bh0 = Wh8[pidx],      Bl0 = Wl8[pidx];
            short8 Bh1 = Wh8[pidx + 16], Bl1 = Wl8[pidx + 16];
            acc0 = __builtin_amdgcn_mfma_f32_16x16x32_bf16(Ah, Bh0, acc0, 0, 0, 0);
            acc1 = __builtin_amdgcn_mfma_f32_16x16x32_bf16(Ah, Bh1, acc1, 0, 0, 0);
            acc0 = __builtin_amdgcn_mfma_f32_16x16x32_bf16(Ah, Bl0, acc0, 0, 0, 0);
            acc1 = __builtin_amdgcn_mfma_f32_16x16x32_bf16(Ah, Bl1, acc1, 0, 0, 0);
            acc0 = __builtin_amdgcn_mfma_f32_16x16x32_bf16(Al, Bh0, acc0, 0, 0, 0);
            acc1 = __builtin_amdgcn_mfma_f32_16x16x32_bf16(Al, Bh1, acc1, 0, 0, 0);
        }
    }

    const int c0 = no * 32 + il, c1 = c0 + 16;
    const float bia0 = bias[c0], bia1 = bias[c1];
    const int hh = no >> 1;
    const int cc0 = c0 & 63, cc1 = c1 & 63;
    const float as0 = a[hh * 128 + cc0],      as1 = a[hh * 128 + cc1];
    const float ad0 = a[hh * 128 + 64 + cc0], ad1 = a[hh * 128 + 64 + cc1];

    float v0[4], v1[4], psrc[4], pdst[4];
    #pragma unroll
    for (int r = 0; r < 4; ++r) {
        v0[r] = acc0[r] + bia0;
        v1[r] = acc1[r] + bia1;
        psrc[r] = v0[r] * as0 + v1[r] * as1;
        pdst[r] = v0[r] * ad0 + v1[r] * ad1;
    }
    #pragma unroll
    for (int off = 8; off >= 1; off >>= 1) {
        #pragma unroll
        for (int r = 0; r < 4; ++r) {
            psrc[r] += __shfl_xor(psrc[r], off);
            pdst[r] += __shfl_xor(pdst[r], off);
        }
    }
    __syncthreads();   // all waves done reading Xh/Xl

    unsigned short* hp = Xh;
    #pragma unroll
    for (int r = 0; r < 4; ++r) {
        int m = mq * 16 + 4 * jg + r;
        int base = (m >> 3) * 128 + (m & 7);
        hp[(c0 >> 6) * 2048 + ((c0 & 63) >> 4) * 512 + base + (c0 & 15) * 8] = f2bf(v0[r]);
        hp[(c1 >> 6) * 2048 + ((c1 & 63) >> 4) * 512 + base + (c1 & 15) * 8] = f2bf(v1[r]);
    }
    if (il == 0) {
        #pragma unroll
        for (int r = 0; r < 4; ++r) {
            lsP[0][no][mq][4 * jg + r] = psrc[r];
            lsP[1][no][mq][4 * jg + r] = pdst[r];
        }
    }
    __syncthreads();

    {
        uint4* dst4 = (uint4*)(hbf_p + (size_t)(b * 32 + tj) * 8192);
        dst4[tid] = ((const uint4*)hp)[tid];
    }
    if (tid < 256) {
        int sd = tid >> 7, rem = tid & 127, h2 = rem >> 5, m = rem & 31;
        float v = lsP[sd][2 * h2][m >> 4][m & 15] + lsP[sd][2 * h2 + 1][m >> 4][m & 15];
        float* dst = sd ? ldst_t : lsrc_t;
        dst[((size_t)b * HH + h2) * NN + tj * 32 + m] = v;
    }
}

// ---------------- Kernel 2: masked softmax attention, PV via MFMA -------------------
// grid 512 x 1024thr (16 waves). b = bid&7 (batch pinned to its XCD's L2 panels),
// i0 = (bid>>3)*16. Wave (h = wv&3, jh = wv>>2): head h, rows i0..i0+15, panels
// jh*8..jh*8+7. MAX-TLP design: 2 blocks/CU x 16 waves = 32 waves/CU; NO prefetch,
// NO sched_barrier, NO in-loop barriers — 8 resident waves/SIMD rotate to hide
// L2/L3 latency (m114), which r13-r15 proved source-level pipelining cannot.
// Live set ~50 VGPR (acc -> AGPRs). Epilogue: 2-phase RMW reduce over jh in LDS.
__global__ __launch_bounds__(1024, 2) void k2_attn(
    const unsigned short* __restrict__ hbf_p, const int* __restrict__ adj,
    const float* __restrict__ lsrc_t, const float* __restrict__ ldst_t,
    float* __restrict__ out)
{
    __shared__ __align__(16) char smem[32768];   // loop: adjw 2KB + ldsTbl 16KB; epi: red[2][16][256]
    __shared__ float lsumS[4][4][16];            // [jh][h][row]

    unsigned int (*adjw)[16] = (unsigned int (*)[16])smem;  // [j-word 0..31][i-row 0..15]
    float* ldsTbl = (float*)(smem + 2048);                  // ldst, 4 heads x 1024

    const int bid = blockIdx.x;
    const int b  = bid & 7;
    const int i0 = (bid >> 3) * 16;
    const int tid = threadIdx.x;
    const int wv = tid >> 6, l = tid & 63, il = l & 15, jg = l >> 4;
    const int h = wv & 3, jh = wv >> 2;

    // ---- prologue: adj bit-pack (wave wv packs row i0+wv) + ldst table ----
    {
        const int* arow = adj + ((size_t)b * NN + i0 + wv) * NN;
        #pragma unroll
        for (int it = 0; it < 16; ++it) {
            int av = arow[it * 64 + l];
            unsigned long long mb = __ballot(av != 0);
            if (l == 0) {
                adjw[2 * it    ][wv] = (unsigned int)mb;
                adjw[2 * it + 1][wv] = (unsigned int)(mb >> 32);
            }
        }
    }
    ((float4*)ldsTbl)[tid] = ((const float4*)(ldst_t + (size_t)b * HH * NN))[tid];
    const float lsrc_v = lsrc_t[((size_t)b * HH + h) * NN + i0 + il];

    __syncthreads();   // adjw + ldsTbl ready

    // ---- mx = max over all j of ldst[h] (valid softmax shift: lrelu monotone) ----
    float mx = -3.4e38f;
    #pragma unroll
    for (int jt = 0; jt < 16; ++jt) mx = fmaxf(mx, ldsTbl[h * 1024 + jt * 64 + l]);
    #pragma unroll
    for (int off = 32; off >= 1; off >>= 1) mx = fmaxf(mx, __shfl_xor(mx, off));
    const float t0  = lsrc_v + mx;
    const float m_r = fmaxf(t0, ALPHA_C * t0);
    float lsum = 0.f;

    f32x4 acc0 = {0.f,0.f,0.f,0.f}, acc1 = acc0, acc2 = acc0, acc3 = acc0;

    // B-frag: panel tj, head h, sub s, lane l at short8 index tj*1024 + h*256 + s*64 + l
    const short8* bfp = (const short8*)(hbf_p + (size_t)b * 32 * 8192);
    const int fb = h * 256 + l;
    const float* ltb = ldsTbl + h * 1024 + jg * 8;

    // ---- main loop: 8 panels for this wave's j-quarter; dead simple, TLP hides ----
    #pragma unroll 2
    for (int t = 0; t < 8; ++t) {
        const int tj = jh * 8 + t;
        short8 c0 = bfp[tj * 1024 + fb +   0];
        short8 c1 = bfp[tj * 1024 + fb +  64];
        short8 c2 = bfp[tj * 1024 + fb + 128];
        short8 c3 = bfp[tj * 1024 + fb + 192];
        const unsigned int bw = adjw[tj][il] >> (jg * 8);
        const float4 dA = *(const float4*)(ltb + tj * 32);
        const float4 dB = *(const float4*)(ltb + tj * 32 + 4);

        short8 af;
        #define PELEM(DV, E) {                                   \
            float s_ = lsrc_v + (DV);                            \
            s_ = fmaxf(s_, ALPHA_C * s_);                        \
            float p_ = __expf(s_ - m_r);                         \
            p_ = ((bw >> (E)) & 1u) ? p_ : 0.f;                  \
            lsum += p_;                                          \
            af[E] = (short)f2bf(p_); }
        PELEM(dA.x, 0) PELEM(dA.y, 1) PELEM(dA.z, 2) PELEM(dA.w, 3)
        PELEM(dB.x, 4) PELEM(dB.y, 5) PELEM(dB.z, 6) PELEM(dB.w, 7)
        #undef PELEM

        acc0 = __builtin_amdgcn_mfma_f32_16x16x32_bf16(af, c0, acc0, 0, 0, 0);
        acc1 = __builtin_amdgcn_mfma_f32_16x16x32_bf16(af, c1, acc1, 0, 0, 0);
        acc2 = __builtin_amdgcn_mfma_f32_16x16x32_bf16(af, c2, acc2, 0, 0, 0);
        acc3 = __builtin_amdgcn_mfma_f32_16x16x32_bf16(af, c3, acc3, 0, 0, 0);
    }

    // ---- lsum partial (this j-quarter): reduce over jg, stash ----
    lsum += __shfl_xor(lsum, 16);
    lsum += __shfl_xor(lsum, 32);
    if (l < 16) lsumS[jh][h][il] = lsum;
    __syncthreads();   // all loop reads of adjw/ldsTbl done; red may overlay

    // ---- 2-phase RMW reduction over jh into red[2][16 rows][256 cols] ----
    float* red = (float*)smem;
    float* rb = red + (jh & 1) * 4096;
    #define STOREALL(OP) {                                                    \
        const int base = (4 * jg) * 256 + h * 64 + il;                        \
        rb[base +   0 +  0] OP acc0[0]; rb[base +   0 + 16] OP acc1[0];       \
        rb[base +   0 + 32] OP acc2[0]; rb[base +   0 + 48] OP acc3[0];       \
        rb[base + 256 +  0] OP acc0[1]; rb[base + 256 + 16] OP acc1[1];       \
        rb[base + 256 + 32] OP acc2[1]; rb[base + 256 + 48] OP acc3[1];       \
        rb[base + 512 +  0] OP acc0[2]; rb[base + 512 + 16] OP acc1[2];       \
        rb[base + 512 + 32] OP acc2[2]; rb[base + 512 + 48] OP acc3[2];       \
        rb[base + 768 +  0] OP acc0[3]; rb[base + 768 + 16] OP acc1[3];       \
        rb[base + 768 + 32] OP acc2[3]; rb[base + 768 + 48] OP acc3[3]; }
    if (jh < 2) STOREALL(=)
    __syncthreads();
    if (jh >= 2) STOREALL(+=)
    __syncthreads();
    #undef STOREALL

    // ---- final: sum the 2 red halves, normalize, coalesced store ----
    #pragma unroll
    for (int e = 0; e < 4; ++e) {
        int flat = e * 1024 + tid;          // 4096 = 16 rows x 256 cols
        int m = flat >> 8, c = flat & 255;
        int h2 = c >> 6;
        float v  = red[flat] + red[4096 + flat];
        float ls = lsumS[0][h2][m] + lsumS[1][h2][m] + lsumS[2][h2][m] + lsumS[3][h2][m];
        out[((size_t)(b * NN + i0 + m)) * COUT + c] = v / ls;
    }
}

extern "C" void kernel_launch(void* const* d_in, const int* in_sizes, int n_in,
                              void* d_out, int out_size, void* d_ws, size_t ws_size,
                              hipStream_t stream) {
    const float* X    = (const float*)d_in[0];
    const int*   adj  = (const int*)  d_in[1];
    const float* W    = (const float*)d_in[2];
    const float* bias = (const float*)d_in[3];
    const float* a    = (const float*)d_in[4];
    float* out = (float*)d_out;

    unsigned short* hbf_p = (unsigned short*)d_ws;                  // 8*32 panels, 4 MB
    float* lsrc_t = (float*)(hbf_p + (size_t)BN * 32 * 8192);       // [b][h][n]
    float* ldst_t = lsrc_t + (size_t)BN * HH * NN;
    unsigned short* Whp = (unsigned short*)(ldst_t + (size_t)BN * HH * NN);  // 128 KB
    unsigned short* Wlp = Whp + 65536;                                        // 128 KB

    k0_wpack<<<32, 256, 0, stream>>>(W, Whp, Wlp);
    k1_gemm<<<256, 1024, 0, stream>>>(X, bias, a, Whp, Wlp, hbf_p, lsrc_t, ldst_t);
    k2_attn<<<BN * (NN / 16), 1024, 0, stream>>>(hbf_p, adj, lsrc_t, ldst_t, out);
}